// Round 3
// baseline (585.113 us; speedup 1.0000x reference)
//
#include <hip/hip_runtime.h>
#include <hip/hip_bf16.h>
#include <math.h>

#define NP 100000
#define KC 64
#define OD 1024
#define EPSF 1e-6f

#define ROWS_PER_BLOCK 128
#define NBLOCKS ((NP + ROWS_PER_BLOCK - 1) / ROWS_PER_BLOCK)  // 782
#define NT 16   // number of 64-wide k-steps

typedef __attribute__((ext_vector_type(8))) short short8;
typedef __attribute__((ext_vector_type(4))) float f32x4;

// ---- ws layout ----
// [0      .. 256)    : logw, 64 floats
// [256    .. 6512)   : per-block double partials (NBLOCKS * 8)
// [8192   .. +256K)  : staged B, 16 steps x 16 KB. Within step t, short-index:
//                      h*4096 + kg*2048 + ct*512 + (g*16+c)*8 + kk
//                      = bf16 of log(otu[ct*16+c][t*64+kg*32+g*8+kk]+eps)
//                      h: 0=hi 1=lo. Lane-linear for both gll staging and
//                      ds_read_b128 frag reads (lane = g*16+c) -> conflict-free.
#define WS_LOGW      0
#define WS_PARTIALS  256
#define WS_BSTAGE    8192

__device__ __forceinline__ unsigned short f32_bf16_rn(float f) {
  unsigned int u = __float_as_uint(f);
  unsigned int r = u + 0x7fffu + ((u >> 16) & 1u);
  return (unsigned short)(r >> 16);
}

__device__ __forceinline__ void gll16(const void* gsrc, void* lds) {
  __builtin_amdgcn_global_load_lds(
      (const __attribute__((address_space(1))) unsigned int*)gsrc,
      (__attribute__((address_space(3))) unsigned int*)lds, 16, 0, 0);
}

__global__ void prep_kernel(const float* __restrict__ otu,
                            const float* __restrict__ comm,
                            unsigned short* __restrict__ bstage,
                            float* __restrict__ logw) {
  int b = blockIdx.x;
  if (b < KC) {
    int c = b & 15, ct = b >> 4;
    for (int k = threadIdx.x; k < OD; k += blockDim.x) {
      float x = logf(otu[b * OD + k] + EPSF);
      unsigned short h = f32_bf16_rn(x);
      float hf = __uint_as_float(((unsigned int)h) << 16);
      unsigned short l = f32_bf16_rn(x - hf);
      int t = k >> 6, kg = (k >> 5) & 1, g = (k >> 3) & 3, kk = k & 7;
      size_t base = (size_t)t * 8192 + (size_t)kg * 2048 + (size_t)ct * 512
                  + (size_t)(g * 16 + c) * 8 + kk;
      bstage[base] = h;           // hi (h=0)
      bstage[base + 4096] = l;    // lo (h=1)
    }
  } else {
    if (threadIdx.x < KC) logw[threadIdx.x] = logf(comm[threadIdx.x] + EPSF);
  }
}

// 4 waves * 32 rows = 128 particle rows per block, all 64 community cols/wave.
// K-step = 64: each row-visit reads 256 B contiguous (DRAM row-buffer friendly),
// B double-buffered in LDS via gll (lane-linear, conflict-free). A loads are
// issued at step-top behind the gll's and consumed within the step; exposed
// latency is covered by 3 blocks/CU in this BW-bound regime.
__global__ __launch_bounds__(256, 3)
void ll_kernel(const float* __restrict__ counts,
               const unsigned short* __restrict__ bstage,
               const float* __restrict__ logw,
               double* __restrict__ partials) {
  __shared__ unsigned short bufB[2][8192];  // 2 x 16 KB

  const int tid = threadIdx.x;
  const int wave = tid >> 6;
  const int lane = tid & 63;
  const int g = lane >> 4;   // k-group within frag
  const int c = lane & 15;   // A-row / B-col within 16-tile
  const int rowBase = blockIdx.x * ROWS_PER_BLOCK + wave * 32;

  f32x4 acc[2][4];
#pragma unroll
  for (int i = 0; i < 2; ++i)
#pragma unroll
    for (int j = 0; j < 4; ++j)
      acc[i][j] = (f32x4){0.f, 0.f, 0.f, 0.f};

  int r0 = rowBase + c;      if (r0 >= NP) r0 = NP - 1;  // tail rows dropped in epilogue
  int r1 = rowBase + 16 + c; if (r1 >= NP) r1 = NP - 1;
  const float* pa0 = counts + (size_t)r0 * OD + g * 8;
  const float* pa1 = counts + (size_t)r1 * OD + g * 8;

  // staging: wave w copies shorts [w*2048, w*2048+2048) of the step's 8192
  const unsigned short* sbase = bstage + (size_t)wave * 2048 + (size_t)lane * 8;

  // ---- prologue: stage t=0 into buf0 ----
  {
    unsigned short* dst = &bufB[0][wave * 2048];
    gll16(sbase, dst);
    gll16(sbase + 512, dst + 512);
    gll16(sbase + 1024, dst + 1024);
    gll16(sbase + 1536, dst + 1536);
  }
  __syncthreads();

  int cur = 0;
  for (int t = 0; t < NT; ++t) {
    const int tn = (t + 1 < NT) ? t + 1 : NT - 1;

    // 1) stage next k-block into the other buffer (4 gll, in flight all step)
    {
      const unsigned short* src = sbase + (size_t)tn * 8192;
      unsigned short* dst = &bufB[cur ^ 1][wave * 2048];
      gll16(src, dst);
      gll16(src + 512, dst + 512);
      gll16(src + 1024, dst + 1024);
      gll16(src + 1536, dst + 1536);
    }

    // 2) A loads for this step: 256 B contiguous per row
    const float* a0p = pa0 + t * 64;
    const float* a1p = pa1 + t * 64;
    float4 A0[2][2], A1[2][2];  // [kg][half]
#pragma unroll
    for (int kg = 0; kg < 2; ++kg) {
      A0[kg][0] = *(const float4*)(a0p + kg * 32);
      A0[kg][1] = *(const float4*)(a0p + kg * 32 + 4);
      A1[kg][0] = *(const float4*)(a1p + kg * 32);
      A1[kg][1] = *(const float4*)(a1p + kg * 32 + 4);
    }

    // 3) per 32-k sub-step: B frags from LDS, pack A, 16 MFMA
#pragma unroll
    for (int kg = 0; kg < 2; ++kg) {
      short8 fbh[4], fbl[4];
#pragma unroll
      for (int ct = 0; ct < 4; ++ct) {
        fbh[ct] = *(const short8*)(&bufB[cur][kg * 2048 + ct * 512 + lane * 8]);
        fbl[ct] = *(const short8*)(&bufB[cur][4096 + kg * 2048 + ct * 512 + lane * 8]);
      }

      union { unsigned int u[4]; short8 v; } ua0, ua1;
      ua0.u[0] = __builtin_amdgcn_perm(__float_as_uint(A0[kg][0].y), __float_as_uint(A0[kg][0].x), 0x07060302u);
      ua0.u[1] = __builtin_amdgcn_perm(__float_as_uint(A0[kg][0].w), __float_as_uint(A0[kg][0].z), 0x07060302u);
      ua0.u[2] = __builtin_amdgcn_perm(__float_as_uint(A0[kg][1].y), __float_as_uint(A0[kg][1].x), 0x07060302u);
      ua0.u[3] = __builtin_amdgcn_perm(__float_as_uint(A0[kg][1].w), __float_as_uint(A0[kg][1].z), 0x07060302u);
      ua1.u[0] = __builtin_amdgcn_perm(__float_as_uint(A1[kg][0].y), __float_as_uint(A1[kg][0].x), 0x07060302u);
      ua1.u[1] = __builtin_amdgcn_perm(__float_as_uint(A1[kg][0].w), __float_as_uint(A1[kg][0].z), 0x07060302u);
      ua1.u[2] = __builtin_amdgcn_perm(__float_as_uint(A1[kg][1].y), __float_as_uint(A1[kg][1].x), 0x07060302u);
      ua1.u[3] = __builtin_amdgcn_perm(__float_as_uint(A1[kg][1].w), __float_as_uint(A1[kg][1].z), 0x07060302u);

#pragma unroll
      for (int ct = 0; ct < 4; ++ct) {
        acc[0][ct] = __builtin_amdgcn_mfma_f32_16x16x32_bf16(ua0.v, fbh[ct], acc[0][ct], 0, 0, 0);
        acc[1][ct] = __builtin_amdgcn_mfma_f32_16x16x32_bf16(ua1.v, fbh[ct], acc[1][ct], 0, 0, 0);
        acc[0][ct] = __builtin_amdgcn_mfma_f32_16x16x32_bf16(ua0.v, fbl[ct], acc[0][ct], 0, 0, 0);
        acc[1][ct] = __builtin_amdgcn_mfma_f32_16x16x32_bf16(ua1.v, fbl[ct], acc[1][ct], 0, 0, 0);
      }
    }

    // everything (A loads, glls, ds_reads) is naturally drained by here;
    // __syncthreads costs no extra stall in this BW-bound regime
    __syncthreads();
    cur ^= 1;
  }

  // ---- epilogue: + logw, logsumexp over 64 cols per row, accumulate rows ----
  float lw[4];
#pragma unroll
  for (int ct = 0; ct < 4; ++ct) lw[ct] = logw[ct * 16 + c];

  double lsum = 0.0;
#pragma unroll
  for (int rt = 0; rt < 2; ++rt) {
#pragma unroll
    for (int r = 0; r < 4; ++r) {
      // lane holds cols {ct*16+c}, row = rowBase + rt*16 + g*4 + r
      float v0 = acc[rt][0][r] + lw[0];
      float v1 = acc[rt][1][r] + lw[1];
      float v2 = acc[rt][2][r] + lw[2];
      float v3 = acc[rt][3][r] + lw[3];
      float m = fmaxf(fmaxf(v0, v1), fmaxf(v2, v3));
      m = fmaxf(m, __shfl_xor(m, 1));
      m = fmaxf(m, __shfl_xor(m, 2));
      m = fmaxf(m, __shfl_xor(m, 4));
      m = fmaxf(m, __shfl_xor(m, 8));
      float s = __expf(v0 - m) + __expf(v1 - m) + __expf(v2 - m) + __expf(v3 - m);
      s += __shfl_xor(s, 1);
      s += __shfl_xor(s, 2);
      s += __shfl_xor(s, 4);
      s += __shfl_xor(s, 8);
      float lse = m + __logf(s);
      int row = rowBase + rt * 16 + g * 4 + r;
      if (c == 0 && row < NP) lsum += (double)lse;
    }
  }
  lsum += __shfl_xor(lsum, 16);
  lsum += __shfl_xor(lsum, 32);

  __shared__ double wpart[4];
  if (lane == 0) wpart[wave] = lsum;
  __syncthreads();
  if (tid == 0) partials[blockIdx.x] = wpart[0] + wpart[1] + wpart[2] + wpart[3];
}

__global__ void finalize_kernel(const double* __restrict__ partials,
                                float* __restrict__ out) {
  double s = 0.0;
  for (int i = threadIdx.x; i < NBLOCKS; i += 256) s += partials[i];
  s += __shfl_xor(s, 1);
  s += __shfl_xor(s, 2);
  s += __shfl_xor(s, 4);
  s += __shfl_xor(s, 8);
  s += __shfl_xor(s, 16);
  s += __shfl_xor(s, 32);
  __shared__ double sp[4];
  int w = threadIdx.x >> 6, lane = threadIdx.x & 63;
  if (lane == 0) sp[w] = s;
  __syncthreads();
  if (threadIdx.x == 0) out[0] = (float)(sp[0] + sp[1] + sp[2] + sp[3]);
}

extern "C" void kernel_launch(void* const* d_in, const int* in_sizes, int n_in,
                              void* d_out, int out_size, void* d_ws, size_t ws_size,
                              hipStream_t stream) {
  const float* counts = (const float*)d_in[0];
  const float* otu    = (const float*)d_in[1];
  const float* comm   = (const float*)d_in[2];
  float* out = (float*)d_out;
  char* ws = (char*)d_ws;

  float* logw          = (float*)(ws + WS_LOGW);
  double* partials     = (double*)(ws + WS_PARTIALS);
  unsigned short* bst  = (unsigned short*)(ws + WS_BSTAGE);

  prep_kernel<<<KC + 1, 256, 0, stream>>>(otu, comm, bst, logw);
  ll_kernel<<<NBLOCKS, 256, 0, stream>>>(counts, bst, logw, partials);
  finalize_kernel<<<1, 256, 0, stream>>>(partials, out);
}

// Round 4
// 564.103 us; speedup vs baseline: 1.0372x; 1.0372x over previous
//
#include <hip/hip_runtime.h>
#include <hip/hip_bf16.h>
#include <math.h>

#define NP 100000
#define KC 64
#define OD 1024
#define EPSF 1e-6f

#define ROWS_PER_BLOCK 128
#define NBLOCKS ((NP + ROWS_PER_BLOCK - 1) / ROWS_PER_BLOCK)  // 782

typedef __attribute__((ext_vector_type(8))) short short8;
typedef __attribute__((ext_vector_type(4))) float f32x4;

// ---- ws layout ----
// [0    .. 256)   : logw, 64 floats
// [256  .. 6512)  : per-block double partials (NBLOCKS * 8)
// [8192 .. +256K) : bstage, frag-ordered B. short-index:
//                   kb*4096 + h*2048 + ct*512 + (g*16+c)*8 + kk
//                   = bf16(h=0:hi,1:lo) of log(otu[ct*16+c][kb*32+g*8+kk]+eps)
//                   One frag read = 1 KB contiguous per wave (fully coalesced).
#define WS_LOGW      0
#define WS_PARTIALS  256
#define WS_BSTAGE    8192

__device__ __forceinline__ unsigned short f32_bf16_rn(float f) {
  unsigned int u = __float_as_uint(f);
  unsigned int r = u + 0x7fffu + ((u >> 16) & 1u);
  return (unsigned short)(r >> 16);
}

__global__ void prep_kernel(const float* __restrict__ otu,
                            const float* __restrict__ comm,
                            unsigned short* __restrict__ bstage,
                            float* __restrict__ logw) {
  int b = blockIdx.x;
  if (b < KC) {
    int c = b & 15, ct = b >> 4;
    for (int k = threadIdx.x; k < OD; k += blockDim.x) {
      float x = logf(otu[b * OD + k] + EPSF);
      unsigned short h = f32_bf16_rn(x);
      float hf = __uint_as_float(((unsigned int)h) << 16);
      unsigned short l = f32_bf16_rn(x - hf);
      int kb = k >> 5, g = (k >> 3) & 3, kk = k & 7;
      size_t base = (size_t)kb * 4096 + (size_t)ct * 512
                  + (size_t)(g * 16 + c) * 8 + kk;
      bstage[base] = h;           // hi (h=0)
      bstage[base + 2048] = l;    // lo (h=1)
    }
  } else {
    if (threadIdx.x < KC) logw[threadIdx.x] = logf(comm[threadIdx.x] + EPSF);
  }
}

// 4 waves * 32 rows = 128 rows/block, all 64 community cols per wave.
// No LDS, no barriers: B frags come straight from L2-resident bstage.
// A is read in K-chunks of 256: per chunk the wave issues all 32 float4
// loads back-to-back -> each of its 32 rows is visited with 1 KB contiguous
// (DRAM page/activate friendly), then packed to bf16 (exact for counts) and
// consumed by 128 MFMAs. Chunk phase rotates per block (p = blockIdx & 3) so
// column offsets are spread across channels GPU-wide; unsynchronized waves
// drift, spreading further.
__global__ __launch_bounds__(256, 2)
void ll_kernel(const float* __restrict__ counts,
               const unsigned short* __restrict__ bstage,
               const float* __restrict__ logw,
               double* __restrict__ partials) {
  const int tid = threadIdx.x;
  const int wave = tid >> 6;
  const int lane = tid & 63;
  const int g = lane >> 4;   // k-group within frag
  const int c = lane & 15;   // A-row / B-col within 16-tile
  const int rowBase = blockIdx.x * ROWS_PER_BLOCK + wave * 32;

  f32x4 acc[2][4];
#pragma unroll
  for (int i = 0; i < 2; ++i)
#pragma unroll
    for (int j = 0; j < 4; ++j)
      acc[i][j] = (f32x4){0.f, 0.f, 0.f, 0.f};

  int r0 = rowBase + c;      if (r0 >= NP) r0 = NP - 1;  // tail rows dropped in epilogue
  int r1 = rowBase + 16 + c; if (r1 >= NP) r1 = NP - 1;
  const float* pa0 = counts + (size_t)r0 * OD + g * 8;
  const float* pa1 = counts + (size_t)r1 * OD + g * 8;

  const int p = blockIdx.x & 3;   // chunk-phase rotation

  for (int ci = 0; ci < 4; ++ci) {
    const int t = (p + ci) & 3;            // K-chunk: cols [t*256, t*256+256)
    const float* a0 = pa0 + t * 256;
    const float* a1 = pa1 + t * 256;

    // 1) burst-issue all 32 A loads (1 KB contiguous per row per visit)
    float4 x0[8], x1[8], y0[8], y1[8];
#pragma unroll
    for (int s = 0; s < 8; ++s) {
      x0[s] = *(const float4*)(a0 + s * 32);
      x1[s] = *(const float4*)(a0 + s * 32 + 4);
      y0[s] = *(const float4*)(a1 + s * 32);
      y1[s] = *(const float4*)(a1 + s * 32 + 4);
    }

    // 2) pack to bf16 (truncation; exact for integer counts). Compiler emits
    //    counted vmcnt per s since loads were issued in order.
    short8 ah0[8], ah1[8];
#pragma unroll
    for (int s = 0; s < 8; ++s) {
      union { unsigned int u[4]; short8 v; } u0, u1;
      u0.u[0] = __builtin_amdgcn_perm(__float_as_uint(x0[s].y), __float_as_uint(x0[s].x), 0x07060302u);
      u0.u[1] = __builtin_amdgcn_perm(__float_as_uint(x0[s].w), __float_as_uint(x0[s].z), 0x07060302u);
      u0.u[2] = __builtin_amdgcn_perm(__float_as_uint(x1[s].y), __float_as_uint(x1[s].x), 0x07060302u);
      u0.u[3] = __builtin_amdgcn_perm(__float_as_uint(x1[s].w), __float_as_uint(x1[s].z), 0x07060302u);
      u1.u[0] = __builtin_amdgcn_perm(__float_as_uint(y0[s].y), __float_as_uint(y0[s].x), 0x07060302u);
      u1.u[1] = __builtin_amdgcn_perm(__float_as_uint(y0[s].w), __float_as_uint(y0[s].z), 0x07060302u);
      u1.u[2] = __builtin_amdgcn_perm(__float_as_uint(y1[s].y), __float_as_uint(y1[s].x), 0x07060302u);
      u1.u[3] = __builtin_amdgcn_perm(__float_as_uint(y1[s].w), __float_as_uint(y1[s].z), 0x07060302u);
      ah0[s] = u0.v;
      ah1[s] = u1.v;
    }

    // 3) compute: per 32-k sub-step, B frags from L2 + 16 MFMA
#pragma unroll
    for (int s = 0; s < 8; ++s) {
      const int kb = t * 8 + s;
      const unsigned short* bb = bstage + (size_t)kb * 4096 + (size_t)lane * 8;
      short8 fbh[4], fbl[4];
#pragma unroll
      for (int ct = 0; ct < 4; ++ct) {
        fbh[ct] = *(const short8*)(bb + ct * 512);
        fbl[ct] = *(const short8*)(bb + 2048 + ct * 512);
      }
#pragma unroll
      for (int ct = 0; ct < 4; ++ct) {
        acc[0][ct] = __builtin_amdgcn_mfma_f32_16x16x32_bf16(ah0[s], fbh[ct], acc[0][ct], 0, 0, 0);
        acc[1][ct] = __builtin_amdgcn_mfma_f32_16x16x32_bf16(ah1[s], fbh[ct], acc[1][ct], 0, 0, 0);
        acc[0][ct] = __builtin_amdgcn_mfma_f32_16x16x32_bf16(ah0[s], fbl[ct], acc[0][ct], 0, 0, 0);
        acc[1][ct] = __builtin_amdgcn_mfma_f32_16x16x32_bf16(ah1[s], fbl[ct], acc[1][ct], 0, 0, 0);
      }
    }
  }

  // ---- epilogue: + logw, logsumexp over 64 cols per row, accumulate rows ----
  float lw[4];
#pragma unroll
  for (int ct = 0; ct < 4; ++ct) lw[ct] = logw[ct * 16 + c];

  double lsum = 0.0;
#pragma unroll
  for (int rt = 0; rt < 2; ++rt) {
#pragma unroll
    for (int r = 0; r < 4; ++r) {
      // lane holds cols {ct*16+c}, row = rowBase + rt*16 + g*4 + r
      float v0 = acc[rt][0][r] + lw[0];
      float v1 = acc[rt][1][r] + lw[1];
      float v2 = acc[rt][2][r] + lw[2];
      float v3 = acc[rt][3][r] + lw[3];
      float m = fmaxf(fmaxf(v0, v1), fmaxf(v2, v3));
      m = fmaxf(m, __shfl_xor(m, 1));
      m = fmaxf(m, __shfl_xor(m, 2));
      m = fmaxf(m, __shfl_xor(m, 4));
      m = fmaxf(m, __shfl_xor(m, 8));
      float s = __expf(v0 - m) + __expf(v1 - m) + __expf(v2 - m) + __expf(v3 - m);
      s += __shfl_xor(s, 1);
      s += __shfl_xor(s, 2);
      s += __shfl_xor(s, 4);
      s += __shfl_xor(s, 8);
      float lse = m + __logf(s);
      int row = rowBase + rt * 16 + g * 4 + r;
      if (c == 0 && row < NP) lsum += (double)lse;
    }
  }
  lsum += __shfl_xor(lsum, 16);
  lsum += __shfl_xor(lsum, 32);

  __shared__ double wpart[4];
  if (lane == 0) wpart[wave] = lsum;
  __syncthreads();
  if (tid == 0) partials[blockIdx.x] = wpart[0] + wpart[1] + wpart[2] + wpart[3];
}

__global__ void finalize_kernel(const double* __restrict__ partials,
                                float* __restrict__ out) {
  double s = 0.0;
  for (int i = threadIdx.x; i < NBLOCKS; i += 256) s += partials[i];
  s += __shfl_xor(s, 1);
  s += __shfl_xor(s, 2);
  s += __shfl_xor(s, 4);
  s += __shfl_xor(s, 8);
  s += __shfl_xor(s, 16);
  s += __shfl_xor(s, 32);
  __shared__ double sp[4];
  int w = threadIdx.x >> 6, lane = threadIdx.x & 63;
  if (lane == 0) sp[w] = s;
  __syncthreads();
  if (threadIdx.x == 0) out[0] = (float)(sp[0] + sp[1] + sp[2] + sp[3]);
}

extern "C" void kernel_launch(void* const* d_in, const int* in_sizes, int n_in,
                              void* d_out, int out_size, void* d_ws, size_t ws_size,
                              hipStream_t stream) {
  const float* counts = (const float*)d_in[0];
  const float* otu    = (const float*)d_in[1];
  const float* comm   = (const float*)d_in[2];
  float* out = (float*)d_out;
  char* ws = (char*)d_ws;

  float* logw          = (float*)(ws + WS_LOGW);
  double* partials     = (double*)(ws + WS_PARTIALS);
  unsigned short* bst  = (unsigned short*)(ws + WS_BSTAGE);

  prep_kernel<<<KC + 1, 256, 0, stream>>>(otu, comm, bst, logw);
  ll_kernel<<<NBLOCKS, 256, 0, stream>>>(counts, bst, logw, partials);
  finalize_kernel<<<1, 256, 0, stream>>>(partials, out);
}